// Round 25
// baseline (216.643 us; speedup 1.0000x reference)
//
#include <hip/hip_runtime.h>

#define B_ 4
#define S_ 1024
#define E_ 2048
#define H_ 32
#define D_ 64

typedef __attribute__((ext_vector_type(4))) float f32x4;
typedef __attribute__((ext_vector_type(8))) short s16x8;
typedef __attribute__((ext_vector_type(4))) unsigned short u16x4;
typedef __attribute__((ext_vector_type(8))) unsigned short u16x8;

__device__ inline unsigned short f2bf(float f) {
  unsigned int u = __float_as_uint(f);
  u += 0x7fff + ((u >> 16) & 1);   // round-to-nearest-even
  return (unsigned short)(u >> 16);
}

__device__ inline void gl_lds16(const unsigned short* g, unsigned short* l) {
  __builtin_amdgcn_global_load_lds(
      (const __attribute__((address_space(1))) unsigned int*)g,
      (__attribute__((address_space(3))) unsigned int*)l,
      16, 0, 0);
}

// ---- one-shot fp32->bf16 convert for X, Wq, Wk, Wv, Wo (region decode) ----
// BW-bound: ~200MB moved; measured ~22us ~= its memory roofline.
__global__ __launch_bounds__(256) void convert_all(
    const float* __restrict__ X, const float* __restrict__ Wq,
    const float* __restrict__ Wk, const float* __restrict__ Wv,
    const float* __restrict__ Wo, unsigned short* __restrict__ Xb,
    unsigned short* __restrict__ Wqb, unsigned short* __restrict__ Wkb,
    unsigned short* __restrict__ Wvb, unsigned short* __restrict__ Wob) {
  const int nX8 = (B_ * S_ * E_) / 8;   // 2^20
  const int nW8 = (E_ * E_) / 8;        // 2^19
  int g = blockIdx.x * 256 + threadIdx.x;
  const float* src;
  unsigned short* dst;
  int idx;
  if (g < nX8) {
    src = X; dst = Xb; idx = g;
  } else {
    int t = g - nX8;
    int wsel = t >> 19;                 // /nW8
    idx = t & (nW8 - 1);
    src = wsel == 0 ? Wq : (wsel == 1 ? Wk : (wsel == 2 ? Wv : Wo));
    dst = wsel == 0 ? Wqb : (wsel == 1 ? Wkb : (wsel == 2 ? Wvb : Wob));
  }
  const float4* p = (const float4*)src + (size_t)idx * 2;
  float4 a = p[0], b = p[1];
  u16x8 o;
  o[0] = f2bf(a.x); o[1] = f2bf(a.y); o[2] = f2bf(a.z); o[3] = f2bf(a.w);
  o[4] = f2bf(b.x); o[5] = f2bf(b.y); o[6] = f2bf(b.z); o[7] = f2bf(b.w);
  *((u16x8*)dst + idx) = o;
}

// ---------------- 128x128 GEMM, BK=64, dbuf, counted vmcnt, 2 blk/CU ------
// FINAL (verified 10x: 215.4-217.0us total):
// 4 waves/256thr, 64KB LDS, 2 blocks/CU. Stage t+2 into the being-read
// buffer AFTER the read-complete barrier -> ~1 full K-tile of prefetch
// distance; counted vmcnt(8) keeps it in flight across the tile-entry
// barrier. T2 both-sides XOR swizzle (bank-conflict 0), T5 setprio, XCD
// swizzle. Do NOT retry: triple-buffer (r7), 8-phase port (r8), 8 waves
// (r11), BK=32 (r13), 32x32 MFMA (r15: structural 8-way LDS conflict),
// single-barrier stage-before-reads (r17: halves prefetch distance).
// MODE 0: fused QKV. Logical N=6144, tn 0-15 -> Q, 16-31 -> K, 32-47 -> V(t).
// MODE 1: O-proj, fp32 out, N=2048.
template <int MODE>
__global__ __launch_bounds__(256) void gemm128(
    const unsigned short* __restrict__ A,
    const unsigned short* __restrict__ W0,
    const unsigned short* __restrict__ W1,
    const unsigned short* __restrict__ W2,
    const float* __restrict__ b0, const float* __restrict__ b1,
    const float* __restrict__ b2,
    unsigned short* __restrict__ O0, unsigned short* __restrict__ O1,
    unsigned short* __restrict__ O2, float* __restrict__ OF) {
  __shared__ __align__(16) unsigned short lA[2][128 * 64];
  __shared__ __align__(16) unsigned short lB[2][128 * 64];
  int tid = threadIdx.x;
  int w = tid >> 6, lane = tid & 63;
  int row16 = lane & 15, grp = lane >> 4;
  int wm = w >> 1, wn = w & 1;           // 2x2 waves; wave tile 64x64
  int srow = tid >> 3;
  int sswz = ((tid & 7) ^ (srow & 7)) * 8;

  int nwg = gridDim.x;
  int bid = blockIdx.x;
  int swz = (bid & 7) * (nwg >> 3) + (bid >> 3);
  const int NT = (MODE == 0) ? 48 : 16;
  int tm = swz / NT, tn = swz % NT;
  int seg = (MODE == 0) ? (tn >> 4) : 0;
  const unsigned short* Bsrc =
      (MODE == 0) ? (seg == 0 ? W0 : (seg == 1 ? W1 : W2)) : W0;
  int rowA0 = tm * 128;
  int rowB0 = (tn - seg * 16) * 128;

  f32x4 acc[4][4] = {};

#define STG4(G, L, R0, K0)                                                  \
  { _Pragma("unroll") for (int c = 0; c < 4; c++) {                         \
      gl_lds16((G) + (size_t)((R0) + c * 32 + srow) * 2048 + (K0) + sswz,   \
               (L) + (c * 32 + w * 8) * 64); } }

  STG4(A, &lA[0][0], rowA0, 0)
  STG4(Bsrc, &lB[0][0], rowB0, 0)
  STG4(A, &lA[1][0], rowA0, 64)
  STG4(Bsrc, &lB[1][0], rowB0, 64)

  int xr = row16 & 7;
  for (int t = 0; t < 32; t++) {
    if (t < 31) asm volatile("s_waitcnt vmcnt(8)" ::: "memory");
    else        asm volatile("s_waitcnt vmcnt(0)" ::: "memory");
    __builtin_amdgcn_sched_barrier(0);
    __builtin_amdgcn_s_barrier();
    __builtin_amdgcn_sched_barrier(0);
    const unsigned short* As = &lA[t & 1][0];
    const unsigned short* Bs = &lB[t & 1][0];
    s16x8 af[2][4], bf[2][4];
#pragma unroll
    for (int kk = 0; kk < 2; kk++) {
      int so = ((kk * 4 + grp) ^ xr) * 8;
#pragma unroll
      for (int i = 0; i < 4; i++)
        af[kk][i] = *(const s16x8*)(As + (wm * 64 + i * 16 + row16) * 64 + so);
#pragma unroll
      for (int j = 0; j < 4; j++)
        bf[kk][j] = *(const s16x8*)(Bs + (wn * 64 + j * 16 + row16) * 64 + so);
    }
    asm volatile("s_waitcnt lgkmcnt(0)" ::: "memory");
    __builtin_amdgcn_sched_barrier(0);
    __builtin_amdgcn_s_barrier();
    __builtin_amdgcn_sched_barrier(0);
    if (t < 30) {
      int k0n = (t + 2) * 64;
      STG4(A, &lA[t & 1][0], rowA0, k0n)
      STG4(Bsrc, &lB[t & 1][0], rowB0, k0n)
    }
    __builtin_amdgcn_s_setprio(1);
#pragma unroll
    for (int kk = 0; kk < 2; kk++)
#pragma unroll
      for (int i = 0; i < 4; i++)
#pragma unroll
        for (int j = 0; j < 4; j++)
          acc[i][j] = __builtin_amdgcn_mfma_f32_16x16x32_bf16(af[kk][i], bf[kk][j], acc[i][j], 0, 0, 0);
    __builtin_amdgcn_s_setprio(0);
  }
#undef STG4

  int row0 = rowA0 + wm * 64 + grp * 4;
  int col0 = (tn - seg * 16) * 128 + wn * 64 + row16;
  if (MODE == 1) {
#pragma unroll
    for (int i = 0; i < 4; i++)
#pragma unroll
      for (int j = 0; j < 4; j++) {
        int col = col0 + j * 16;
        float bvv = b0[col];
#pragma unroll
        for (int r = 0; r < 4; r++)
          OF[(size_t)(row0 + i * 16 + r) * 2048 + col] = acc[i][j][r] + bvv;
      }
  } else if (seg == 0) {
    const float QSC = 0.18033688011112042f;  // 0.125 * log2(e)
#pragma unroll
    for (int i = 0; i < 4; i++)
#pragma unroll
      for (int j = 0; j < 4; j++) {
        int col = col0 + j * 16;
        float bvv = b0[col];
#pragma unroll
        for (int r = 0; r < 4; r++)
          O0[(size_t)(row0 + i * 16 + r) * 2048 + col] = f2bf((acc[i][j][r] + bvv) * QSC);
      }
  } else if (seg == 1) {
#pragma unroll
    for (int i = 0; i < 4; i++)
#pragma unroll
      for (int j = 0; j < 4; j++) {
        int col = col0 + j * 16;
        float bvv = b1[col];
#pragma unroll
        for (int r = 0; r < 4; r++)
          O1[(size_t)(row0 + i * 16 + r) * 2048 + col] = f2bf(acc[i][j][r] + bvv);
      }
  } else {
#pragma unroll
    for (int i = 0; i < 4; i++)
#pragma unroll
      for (int j = 0; j < 4; j++) {
        int col = col0 + j * 16;
        float bvv = b2[col];
        int hh = col >> 6, dd = col & 63;
        int rowb = row0 + i * 16;
        int bb = rowb >> 10, s0v = rowb & 1023;
        u16x4 pk;
#pragma unroll
        for (int r = 0; r < 4; r++) pk[r] = f2bf(acc[i][j][r] + bvv);
        *(u16x4*)(O2 + (((size_t)(bb * H_ + hh)) * D_ + dd) * S_ + s0v) = pk;
      }
  }
}

// ---------------- flash attention (paired-causal, r6 decode + setprio) -----
// Block = (b, h, pair p): q-groups p and 15-p share K/V LDS staging -> every
// block does 17 chunk-steps. Scores pre-scaled by log2(e) -> exp2f.
// T5: setprio(1) around MFMA clusters.
__global__ __launch_bounds__(256, 4) void attnk(const unsigned short* __restrict__ Q,
                                                const unsigned short* __restrict__ K,
                                                const unsigned short* __restrict__ Vt,
                                                unsigned short* __restrict__ ctx) {
  __shared__ unsigned short KT[2][64 * 64];
  __shared__ unsigned short VT[2][64 * 64];
  __shared__ unsigned short Pl[4][16 * 64];
  int tid = threadIdx.x;
  int w = tid >> 6, lane = tid & 63;
  int row16 = lane & 15, grp = lane >> 4;
  int bid = blockIdx.x;
  int bh = bid >> 3;           // r6 decode (best-measured)
  int p = bid & 7;
  int b = bh >> 5, h = bh & 31;
  int qgA = p, qgB = 15 - p;
  int qA = qgA * 64 + w * 16 + row16;
  int qB = qgB * 64 + w * 16 + row16;
  int nkc = qgB + 1;

  const unsigned short* qpA = Q + ((size_t)(b * S_ + qA)) * E_ + h * D_ + grp * 8;
  const unsigned short* qpB = Q + ((size_t)(b * S_ + qB)) * E_ + h * D_ + grp * 8;
  s16x8 qfA0 = *(const s16x8*)(qpA);
  s16x8 qfA1 = *(const s16x8*)(qpA + 32);
  s16x8 qfB0 = *(const s16x8*)(qpB);
  s16x8 qfB1 = *(const s16x8*)(qpB + 32);

  f32x4 oaccA[4] = {}, oaccB[4] = {};
  float mA = -1e30f, lAr = 0.f, mB = -1e30f, lBr = 0.f;

  int trow = tid >> 3;
  int tslot = tid & 7;
  const unsigned short* Kg = K + ((size_t)(b * S_)) * E_ + h * D_;
  const unsigned short* Vg = Vt + (((size_t)(b * H_ + h)) * D_) * S_;
  unsigned short* P = Pl[w];

  auto tstep = [&](s16x8 q0f, s16x8 q1f, int qloc, f32x4* oa, float& mr,
                   float& lr, bool diag, const unsigned short* Kt,
                   const unsigned short* Vl) {
    f32x4 s[4];
    __builtin_amdgcn_s_setprio(1);
#pragma unroll
    for (int j = 0; j < 4; j++) {
      int krow = 16 * j + row16;
      s16x8 kf0 = *(const s16x8*)(Kt + krow * 64 + ((grp ^ (krow & 7)) * 8));
      s16x8 kf1 = *(const s16x8*)(Kt + krow * 64 + (((grp + 4) ^ (krow & 7)) * 8));
      f32x4 a = {};
      a = __builtin_amdgcn_mfma_f32_16x16x32_bf16(kf0, q0f, a, 0, 0, 0);
      a = __builtin_amdgcn_mfma_f32_16x16x32_bf16(kf1, q1f, a, 0, 0, 0);
      s[j] = a;
    }
    __builtin_amdgcn_s_setprio(0);
    float mx = -1e30f;
    if (diag) {
#pragma unroll
      for (int j = 0; j < 4; j++)
#pragma unroll
        for (int r = 0; r < 4; r++) {
          int key = 16 * j + grp * 4 + r;
          float sv = (key <= qloc) ? s[j][r] : -1e30f;
          s[j][r] = sv;
          mx = fmaxf(mx, sv);
        }
    } else {
#pragma unroll
      for (int j = 0; j < 4; j++)
#pragma unroll
        for (int r = 0; r < 4; r++) mx = fmaxf(mx, s[j][r]);
    }
    mx = fmaxf(mx, __shfl_xor(mx, 16));
    mx = fmaxf(mx, __shfl_xor(mx, 32));
    float mn = fmaxf(mr, mx);
    float sc = exp2f(mr - mn);
    mr = mn;
    float rs = 0.f;
#pragma unroll
    for (int j = 0; j < 4; j++)
#pragma unroll
      for (int r = 0; r < 4; r++) {
        float e = exp2f(s[j][r] - mn);
        s[j][r] = e;
        rs += e;
      }
    rs += __shfl_xor(rs, 16);
    rs += __shfl_xor(rs, 32);
    lr = lr * sc + rs;
#pragma unroll
    for (int dt = 0; dt < 4; dt++) oa[dt] *= sc;
#pragma unroll
    for (int j = 0; j < 4; j++) {
      u16x4 pk;
#pragma unroll
      for (int r = 0; r < 4; r++) pk[r] = f2bf(s[j][r]);
      int s8 = 4 * j + grp;
      *(u16x4*)(P + row16 * 64 + ((s8 * 4) ^ ((row16 & 7) << 3))) = pk;
    }
    s16x8 pb0 = *(const s16x8*)(P + row16 * 64 + ((grp * 8) ^ ((row16 & 7) << 3)));
    s16x8 pb1 = *(const s16x8*)(P + row16 * 64 + (((4 + grp) * 8) ^ ((row16 & 7) << 3)));
    __builtin_amdgcn_s_setprio(1);
#pragma unroll
    for (int dt = 0; dt < 4; dt++) {
      int drow = dt * 16 + row16;
      s16x8 vf0 = *(const s16x8*)(Vl + drow * 64 + ((grp ^ (drow & 7)) * 8));
      s16x8 vf1 = *(const s16x8*)(Vl + drow * 64 + (((grp + 4) ^ (drow & 7)) * 8));
      oa[dt] = __builtin_amdgcn_mfma_f32_16x16x32_bf16(vf0, pb0, oa[dt], 0, 0, 0);
      oa[dt] = __builtin_amdgcn_mfma_f32_16x16x32_bf16(vf1, pb1, oa[dt], 0, 0, 0);
    }
    __builtin_amdgcn_s_setprio(0);
  };

#pragma unroll
  for (int c = 0; c < 2; c++) {
    int krow = c * 32 + trow;
    gl_lds16(Kg + (size_t)krow * E_ + ((tslot ^ (krow & 7)) * 8),
             &KT[0][0] + c * 2048 + w * 512);
    gl_lds16(Vg + (size_t)krow * S_ + ((tslot ^ (krow & 7)) * 8),
             &VT[0][0] + c * 2048 + w * 512);
  }
  __syncthreads();

  for (int kc = 0; kc < nkc; kc++) {
    int cur = kc & 1;
    if (kc + 1 < nkc) {
      int k0n = (kc + 1) * 64;
      int nxt = cur ^ 1;
#pragma unroll
      for (int c = 0; c < 2; c++) {
        int krow = c * 32 + trow;
        gl_lds16(Kg + (size_t)(k0n + krow) * E_ + ((tslot ^ (krow & 7)) * 8),
                 &KT[nxt][0] + c * 2048 + w * 512);
        gl_lds16(Vg + (size_t)krow * S_ + k0n + ((tslot ^ (krow & 7)) * 8),
                 &VT[nxt][0] + c * 2048 + w * 512);
      }
    }
    int k0 = kc * 64;
    const unsigned short* Kt = &KT[cur][0];
    const unsigned short* Vl = &VT[cur][0];

    tstep(qfB0, qfB1, qB - k0, oaccB, mB, lBr, kc == qgB, Kt, Vl);
    if (kc <= qgA)
      tstep(qfA0, qfA1, qA - k0, oaccA, mA, lAr, kc == qgA, Kt, Vl);
    __syncthreads();
  }

  float invB = 1.0f / lBr, invA = 1.0f / lAr;
  unsigned short* cpB = ctx + ((size_t)(b * S_ + qB)) * E_ + h * D_;
  unsigned short* cpA = ctx + ((size_t)(b * S_ + qA)) * E_ + h * D_;
#pragma unroll
  for (int dt = 0; dt < 4; dt++) {
    u16x4 oB, oA;
#pragma unroll
    for (int r = 0; r < 4; r++) {
      oB[r] = f2bf(oaccB[dt][r] * invB);
      oA[r] = f2bf(oaccA[dt][r] * invA);
    }
    *(u16x4*)(cpB + dt * 16 + grp * 4) = oB;
    *(u16x4*)(cpA + dt * 16 + grp * 4) = oA;
  }
}

extern "C" void kernel_launch(void* const* d_in, const int* in_sizes, int n_in,
                              void* d_out, int out_size, void* d_ws, size_t ws_size,
                              hipStream_t stream) {
  const float* X    = (const float*)d_in[0];
  const float* Wq   = (const float*)d_in[2];
  const float* bq   = (const float*)d_in[3];
  const float* Wk   = (const float*)d_in[4];
  const float* bk   = (const float*)d_in[5];
  const float* Wv   = (const float*)d_in[6];
  const float* bv   = (const float*)d_in[7];
  const float* Wo   = (const float*)d_in[8];
  const float* bo   = (const float*)d_in[9];
  float* out = (float*)d_out;

  // ws:    [0,16)MB Xbf (ctx after attn); [16,24) Wq; [24,32) Wk; [32,40) Wv;
  //        [40,56) Vt; [56,64) Wo
  // d_out: [0,16)MB Qbf; [16,32) Kbf (dead before gemm128<1> writes out)
  char* ws = (char*)d_ws;
  unsigned short* Xbf  = (unsigned short*)ws;
  unsigned short* Wqbf = (unsigned short*)(ws + (16u << 20));
  unsigned short* Wkbf = Wqbf + (size_t)E_ * E_;
  unsigned short* Wvbf = Wkbf + (size_t)E_ * E_;
  unsigned short* Vt   = (unsigned short*)(ws + (40u << 20));
  unsigned short* Wobf = (unsigned short*)(ws + (56u << 20));
  unsigned short* Qbf  = (unsigned short*)d_out;
  unsigned short* Kbf  = Qbf + (size_t)(B_ * S_) * E_;

  const int M = B_ * S_;   // 4096
  const int nX8 = (B_ * S_ * E_) / 8;
  const int nW8 = (E_ * E_) / 8;

  convert_all<<<(nX8 + 4 * nW8) / 256, 256, 0, stream>>>(
      X, Wq, Wk, Wv, Wo, Xbf, Wqbf, Wkbf, Wvbf, Wobf);

  gemm128<0><<<(M / 128) * 48, 256, 0, stream>>>(
      Xbf, Wqbf, Wkbf, Wvbf, bq, bk, bv, Qbf, Kbf, Vt, nullptr);

  attnk<<<B_ * H_ * 8, 256, 0, stream>>>(Qbf, Kbf, Vt, Xbf);

  gemm128<1><<<(M / 128) * 16, 256, 0, stream>>>(
      Xbf, Wobf, nullptr, nullptr, bo, nullptr, nullptr,
      nullptr, nullptr, nullptr, out);
}

// Round 26
// 215.371 us; speedup vs baseline: 1.0059x; 1.0059x over previous
//
#include <hip/hip_runtime.h>

#define B_ 4
#define S_ 1024
#define E_ 2048
#define H_ 32
#define D_ 64

typedef __attribute__((ext_vector_type(4))) float f32x4;
typedef __attribute__((ext_vector_type(8))) short s16x8;
typedef __attribute__((ext_vector_type(4))) unsigned short u16x4;
typedef __attribute__((ext_vector_type(8))) unsigned short u16x8;

__device__ inline unsigned short f2bf(float f) {
  unsigned int u = __float_as_uint(f);
  u += 0x7fff + ((u >> 16) & 1);   // round-to-nearest-even
  return (unsigned short)(u >> 16);
}

__device__ inline void gl_lds16(const unsigned short* g, unsigned short* l) {
  __builtin_amdgcn_global_load_lds(
      (const __attribute__((address_space(1))) unsigned int*)g,
      (__attribute__((address_space(3))) unsigned int*)l,
      16, 0, 0);
}

// ---- one-shot fp32->bf16 convert for X, Wq, Wk, Wv, Wo (region decode) ----
// BW-bound: ~200MB moved; measured ~22us ~= its memory roofline.
__global__ __launch_bounds__(256) void convert_all(
    const float* __restrict__ X, const float* __restrict__ Wq,
    const float* __restrict__ Wk, const float* __restrict__ Wv,
    const float* __restrict__ Wo, unsigned short* __restrict__ Xb,
    unsigned short* __restrict__ Wqb, unsigned short* __restrict__ Wkb,
    unsigned short* __restrict__ Wvb, unsigned short* __restrict__ Wob) {
  const int nX8 = (B_ * S_ * E_) / 8;   // 2^20
  const int nW8 = (E_ * E_) / 8;        // 2^19
  int g = blockIdx.x * 256 + threadIdx.x;
  const float* src;
  unsigned short* dst;
  int idx;
  if (g < nX8) {
    src = X; dst = Xb; idx = g;
  } else {
    int t = g - nX8;
    int wsel = t >> 19;                 // /nW8
    idx = t & (nW8 - 1);
    src = wsel == 0 ? Wq : (wsel == 1 ? Wk : (wsel == 2 ? Wv : Wo));
    dst = wsel == 0 ? Wqb : (wsel == 1 ? Wkb : (wsel == 2 ? Wvb : Wob));
  }
  const float4* p = (const float4*)src + (size_t)idx * 2;
  float4 a = p[0], b = p[1];
  u16x8 o;
  o[0] = f2bf(a.x); o[1] = f2bf(a.y); o[2] = f2bf(a.z); o[3] = f2bf(a.w);
  o[4] = f2bf(b.x); o[5] = f2bf(b.y); o[6] = f2bf(b.z); o[7] = f2bf(b.w);
  *((u16x8*)dst + idx) = o;
}

// ---------------- 128x128 GEMM, BK=64, dbuf, counted vmcnt, 2 blk/CU ------
// FINAL (verified 11x: 215.4-217.0us total):
// 4 waves/256thr, 64KB LDS, 2 blocks/CU. Stage t+2 into the being-read
// buffer AFTER the read-complete barrier -> ~1 full K-tile of prefetch
// distance; counted vmcnt(8) keeps it in flight across the tile-entry
// barrier. T2 both-sides XOR swizzle (bank-conflict 0), T5 setprio, XCD
// swizzle. Do NOT retry: triple-buffer (r7), 8-phase port (r8), 8 waves
// (r11), BK=32 (r13), 32x32 MFMA (r15: structural 8-way LDS conflict),
// single-barrier stage-before-reads (r17: halves prefetch distance).
// MODE 0: fused QKV. Logical N=6144, tn 0-15 -> Q, 16-31 -> K, 32-47 -> V(t).
// MODE 1: O-proj, fp32 out, N=2048.
template <int MODE>
__global__ __launch_bounds__(256) void gemm128(
    const unsigned short* __restrict__ A,
    const unsigned short* __restrict__ W0,
    const unsigned short* __restrict__ W1,
    const unsigned short* __restrict__ W2,
    const float* __restrict__ b0, const float* __restrict__ b1,
    const float* __restrict__ b2,
    unsigned short* __restrict__ O0, unsigned short* __restrict__ O1,
    unsigned short* __restrict__ O2, float* __restrict__ OF) {
  __shared__ __align__(16) unsigned short lA[2][128 * 64];
  __shared__ __align__(16) unsigned short lB[2][128 * 64];
  int tid = threadIdx.x;
  int w = tid >> 6, lane = tid & 63;
  int row16 = lane & 15, grp = lane >> 4;
  int wm = w >> 1, wn = w & 1;           // 2x2 waves; wave tile 64x64
  int srow = tid >> 3;
  int sswz = ((tid & 7) ^ (srow & 7)) * 8;

  int nwg = gridDim.x;
  int bid = blockIdx.x;
  int swz = (bid & 7) * (nwg >> 3) + (bid >> 3);
  const int NT = (MODE == 0) ? 48 : 16;
  int tm = swz / NT, tn = swz % NT;
  int seg = (MODE == 0) ? (tn >> 4) : 0;
  const unsigned short* Bsrc =
      (MODE == 0) ? (seg == 0 ? W0 : (seg == 1 ? W1 : W2)) : W0;
  int rowA0 = tm * 128;
  int rowB0 = (tn - seg * 16) * 128;

  f32x4 acc[4][4] = {};

#define STG4(G, L, R0, K0)                                                  \
  { _Pragma("unroll") for (int c = 0; c < 4; c++) {                         \
      gl_lds16((G) + (size_t)((R0) + c * 32 + srow) * 2048 + (K0) + sswz,   \
               (L) + (c * 32 + w * 8) * 64); } }

  STG4(A, &lA[0][0], rowA0, 0)
  STG4(Bsrc, &lB[0][0], rowB0, 0)
  STG4(A, &lA[1][0], rowA0, 64)
  STG4(Bsrc, &lB[1][0], rowB0, 64)

  int xr = row16 & 7;
  for (int t = 0; t < 32; t++) {
    if (t < 31) asm volatile("s_waitcnt vmcnt(8)" ::: "memory");
    else        asm volatile("s_waitcnt vmcnt(0)" ::: "memory");
    __builtin_amdgcn_sched_barrier(0);
    __builtin_amdgcn_s_barrier();
    __builtin_amdgcn_sched_barrier(0);
    const unsigned short* As = &lA[t & 1][0];
    const unsigned short* Bs = &lB[t & 1][0];
    s16x8 af[2][4], bf[2][4];
#pragma unroll
    for (int kk = 0; kk < 2; kk++) {
      int so = ((kk * 4 + grp) ^ xr) * 8;
#pragma unroll
      for (int i = 0; i < 4; i++)
        af[kk][i] = *(const s16x8*)(As + (wm * 64 + i * 16 + row16) * 64 + so);
#pragma unroll
      for (int j = 0; j < 4; j++)
        bf[kk][j] = *(const s16x8*)(Bs + (wn * 64 + j * 16 + row16) * 64 + so);
    }
    asm volatile("s_waitcnt lgkmcnt(0)" ::: "memory");
    __builtin_amdgcn_sched_barrier(0);
    __builtin_amdgcn_s_barrier();
    __builtin_amdgcn_sched_barrier(0);
    if (t < 30) {
      int k0n = (t + 2) * 64;
      STG4(A, &lA[t & 1][0], rowA0, k0n)
      STG4(Bsrc, &lB[t & 1][0], rowB0, k0n)
    }
    __builtin_amdgcn_s_setprio(1);
#pragma unroll
    for (int kk = 0; kk < 2; kk++)
#pragma unroll
      for (int i = 0; i < 4; i++)
#pragma unroll
        for (int j = 0; j < 4; j++)
          acc[i][j] = __builtin_amdgcn_mfma_f32_16x16x32_bf16(af[kk][i], bf[kk][j], acc[i][j], 0, 0, 0);
    __builtin_amdgcn_s_setprio(0);
  }
#undef STG4

  int row0 = rowA0 + wm * 64 + grp * 4;
  int col0 = (tn - seg * 16) * 128 + wn * 64 + row16;
  if (MODE == 1) {
#pragma unroll
    for (int i = 0; i < 4; i++)
#pragma unroll
      for (int j = 0; j < 4; j++) {
        int col = col0 + j * 16;
        float bvv = b0[col];
#pragma unroll
        for (int r = 0; r < 4; r++)
          OF[(size_t)(row0 + i * 16 + r) * 2048 + col] = acc[i][j][r] + bvv;
      }
  } else if (seg == 0) {
    const float QSC = 0.18033688011112042f;  // 0.125 * log2(e)
#pragma unroll
    for (int i = 0; i < 4; i++)
#pragma unroll
      for (int j = 0; j < 4; j++) {
        int col = col0 + j * 16;
        float bvv = b0[col];
#pragma unroll
        for (int r = 0; r < 4; r++)
          O0[(size_t)(row0 + i * 16 + r) * 2048 + col] = f2bf((acc[i][j][r] + bvv) * QSC);
      }
  } else if (seg == 1) {
#pragma unroll
    for (int i = 0; i < 4; i++)
#pragma unroll
      for (int j = 0; j < 4; j++) {
        int col = col0 + j * 16;
        float bvv = b1[col];
#pragma unroll
        for (int r = 0; r < 4; r++)
          O1[(size_t)(row0 + i * 16 + r) * 2048 + col] = f2bf(acc[i][j][r] + bvv);
      }
  } else {
#pragma unroll
    for (int i = 0; i < 4; i++)
#pragma unroll
      for (int j = 0; j < 4; j++) {
        int col = col0 + j * 16;
        float bvv = b2[col];
        int hh = col >> 6, dd = col & 63;
        int rowb = row0 + i * 16;
        int bb = rowb >> 10, s0v = rowb & 1023;
        u16x4 pk;
#pragma unroll
        for (int r = 0; r < 4; r++) pk[r] = f2bf(acc[i][j][r] + bvv);
        *(u16x4*)(O2 + (((size_t)(bb * H_ + hh)) * D_ + dd) * S_ + s0v) = pk;
      }
  }
}

// ---------------- flash attention (paired-causal, r6 decode + setprio) -----
// Block = (b, h, pair p): q-groups p and 15-p share K/V LDS staging -> every
// block does 17 chunk-steps. Scores pre-scaled by log2(e) -> exp2f.
// T5: setprio(1) around MFMA clusters.
__global__ __launch_bounds__(256, 4) void attnk(const unsigned short* __restrict__ Q,
                                                const unsigned short* __restrict__ K,
                                                const unsigned short* __restrict__ Vt,
                                                unsigned short* __restrict__ ctx) {
  __shared__ unsigned short KT[2][64 * 64];
  __shared__ unsigned short VT[2][64 * 64];
  __shared__ unsigned short Pl[4][16 * 64];
  int tid = threadIdx.x;
  int w = tid >> 6, lane = tid & 63;
  int row16 = lane & 15, grp = lane >> 4;
  int bid = blockIdx.x;
  int bh = bid >> 3;           // r6 decode (best-measured)
  int p = bid & 7;
  int b = bh >> 5, h = bh & 31;
  int qgA = p, qgB = 15 - p;
  int qA = qgA * 64 + w * 16 + row16;
  int qB = qgB * 64 + w * 16 + row16;
  int nkc = qgB + 1;

  const unsigned short* qpA = Q + ((size_t)(b * S_ + qA)) * E_ + h * D_ + grp * 8;
  const unsigned short* qpB = Q + ((size_t)(b * S_ + qB)) * E_ + h * D_ + grp * 8;
  s16x8 qfA0 = *(const s16x8*)(qpA);
  s16x8 qfA1 = *(const s16x8*)(qpA + 32);
  s16x8 qfB0 = *(const s16x8*)(qpB);
  s16x8 qfB1 = *(const s16x8*)(qpB + 32);

  f32x4 oaccA[4] = {}, oaccB[4] = {};
  float mA = -1e30f, lAr = 0.f, mB = -1e30f, lBr = 0.f;

  int trow = tid >> 3;
  int tslot = tid & 7;
  const unsigned short* Kg = K + ((size_t)(b * S_)) * E_ + h * D_;
  const unsigned short* Vg = Vt + (((size_t)(b * H_ + h)) * D_) * S_;
  unsigned short* P = Pl[w];

  auto tstep = [&](s16x8 q0f, s16x8 q1f, int qloc, f32x4* oa, float& mr,
                   float& lr, bool diag, const unsigned short* Kt,
                   const unsigned short* Vl) {
    f32x4 s[4];
    __builtin_amdgcn_s_setprio(1);
#pragma unroll
    for (int j = 0; j < 4; j++) {
      int krow = 16 * j + row16;
      s16x8 kf0 = *(const s16x8*)(Kt + krow * 64 + ((grp ^ (krow & 7)) * 8));
      s16x8 kf1 = *(const s16x8*)(Kt + krow * 64 + (((grp + 4) ^ (krow & 7)) * 8));
      f32x4 a = {};
      a = __builtin_amdgcn_mfma_f32_16x16x32_bf16(kf0, q0f, a, 0, 0, 0);
      a = __builtin_amdgcn_mfma_f32_16x16x32_bf16(kf1, q1f, a, 0, 0, 0);
      s[j] = a;
    }
    __builtin_amdgcn_s_setprio(0);
    float mx = -1e30f;
    if (diag) {
#pragma unroll
      for (int j = 0; j < 4; j++)
#pragma unroll
        for (int r = 0; r < 4; r++) {
          int key = 16 * j + grp * 4 + r;
          float sv = (key <= qloc) ? s[j][r] : -1e30f;
          s[j][r] = sv;
          mx = fmaxf(mx, sv);
        }
    } else {
#pragma unroll
      for (int j = 0; j < 4; j++)
#pragma unroll
        for (int r = 0; r < 4; r++) mx = fmaxf(mx, s[j][r]);
    }
    mx = fmaxf(mx, __shfl_xor(mx, 16));
    mx = fmaxf(mx, __shfl_xor(mx, 32));
    float mn = fmaxf(mr, mx);
    float sc = exp2f(mr - mn);
    mr = mn;
    float rs = 0.f;
#pragma unroll
    for (int j = 0; j < 4; j++)
#pragma unroll
      for (int r = 0; r < 4; r++) {
        float e = exp2f(s[j][r] - mn);
        s[j][r] = e;
        rs += e;
      }
    rs += __shfl_xor(rs, 16);
    rs += __shfl_xor(rs, 32);
    lr = lr * sc + rs;
#pragma unroll
    for (int dt = 0; dt < 4; dt++) oa[dt] *= sc;
#pragma unroll
    for (int j = 0; j < 4; j++) {
      u16x4 pk;
#pragma unroll
      for (int r = 0; r < 4; r++) pk[r] = f2bf(s[j][r]);
      int s8 = 4 * j + grp;
      *(u16x4*)(P + row16 * 64 + ((s8 * 4) ^ ((row16 & 7) << 3))) = pk;
    }
    s16x8 pb0 = *(const s16x8*)(P + row16 * 64 + ((grp * 8) ^ ((row16 & 7) << 3)));
    s16x8 pb1 = *(const s16x8*)(P + row16 * 64 + (((4 + grp) * 8) ^ ((row16 & 7) << 3)));
    __builtin_amdgcn_s_setprio(1);
#pragma unroll
    for (int dt = 0; dt < 4; dt++) {
      int drow = dt * 16 + row16;
      s16x8 vf0 = *(const s16x8*)(Vl + drow * 64 + ((grp ^ (drow & 7)) * 8));
      s16x8 vf1 = *(const s16x8*)(Vl + drow * 64 + (((grp + 4) ^ (drow & 7)) * 8));
      oa[dt] = __builtin_amdgcn_mfma_f32_16x16x32_bf16(vf0, pb0, oa[dt], 0, 0, 0);
      oa[dt] = __builtin_amdgcn_mfma_f32_16x16x32_bf16(vf1, pb1, oa[dt], 0, 0, 0);
    }
    __builtin_amdgcn_s_setprio(0);
  };

#pragma unroll
  for (int c = 0; c < 2; c++) {
    int krow = c * 32 + trow;
    gl_lds16(Kg + (size_t)krow * E_ + ((tslot ^ (krow & 7)) * 8),
             &KT[0][0] + c * 2048 + w * 512);
    gl_lds16(Vg + (size_t)krow * S_ + ((tslot ^ (krow & 7)) * 8),
             &VT[0][0] + c * 2048 + w * 512);
  }
  __syncthreads();

  for (int kc = 0; kc < nkc; kc++) {
    int cur = kc & 1;
    if (kc + 1 < nkc) {
      int k0n = (kc + 1) * 64;
      int nxt = cur ^ 1;
#pragma unroll
      for (int c = 0; c < 2; c++) {
        int krow = c * 32 + trow;
        gl_lds16(Kg + (size_t)(k0n + krow) * E_ + ((tslot ^ (krow & 7)) * 8),
                 &KT[nxt][0] + c * 2048 + w * 512);
        gl_lds16(Vg + (size_t)krow * S_ + k0n + ((tslot ^ (krow & 7)) * 8),
                 &VT[nxt][0] + c * 2048 + w * 512);
      }
    }
    int k0 = kc * 64;
    const unsigned short* Kt = &KT[cur][0];
    const unsigned short* Vl = &VT[cur][0];

    tstep(qfB0, qfB1, qB - k0, oaccB, mB, lBr, kc == qgB, Kt, Vl);
    if (kc <= qgA)
      tstep(qfA0, qfA1, qA - k0, oaccA, mA, lAr, kc == qgA, Kt, Vl);
    __syncthreads();
  }

  float invB = 1.0f / lBr, invA = 1.0f / lAr;
  unsigned short* cpB = ctx + ((size_t)(b * S_ + qB)) * E_ + h * D_;
  unsigned short* cpA = ctx + ((size_t)(b * S_ + qA)) * E_ + h * D_;
#pragma unroll
  for (int dt = 0; dt < 4; dt++) {
    u16x4 oB, oA;
#pragma unroll
    for (int r = 0; r < 4; r++) {
      oB[r] = f2bf(oaccB[dt][r] * invB);
      oA[r] = f2bf(oaccA[dt][r] * invA);
    }
    *(u16x4*)(cpB + dt * 16 + grp * 4) = oB;
    *(u16x4*)(cpA + dt * 16 + grp * 4) = oA;
  }
}

extern "C" void kernel_launch(void* const* d_in, const int* in_sizes, int n_in,
                              void* d_out, int out_size, void* d_ws, size_t ws_size,
                              hipStream_t stream) {
  const float* X    = (const float*)d_in[0];
  const float* Wq   = (const float*)d_in[2];
  const float* bq   = (const float*)d_in[3];
  const float* Wk   = (const float*)d_in[4];
  const float* bk   = (const float*)d_in[5];
  const float* Wv   = (const float*)d_in[6];
  const float* bv   = (const float*)d_in[7];
  const float* Wo   = (const float*)d_in[8];
  const float* bo   = (const float*)d_in[9];
  float* out = (float*)d_out;

  // ws:    [0,16)MB Xbf (ctx after attn); [16,24) Wq; [24,32) Wk; [32,40) Wv;
  //        [40,56) Vt; [56,64) Wo
  // d_out: [0,16)MB Qbf; [16,32) Kbf (dead before gemm128<1> writes out)
  char* ws = (char*)d_ws;
  unsigned short* Xbf  = (unsigned short*)ws;
  unsigned short* Wqbf = (unsigned short*)(ws + (16u << 20));
  unsigned short* Wkbf = Wqbf + (size_t)E_ * E_;
  unsigned short* Wvbf = Wkbf + (size_t)E_ * E_;
  unsigned short* Vt   = (unsigned short*)(ws + (40u << 20));
  unsigned short* Wobf = (unsigned short*)(ws + (56u << 20));
  unsigned short* Qbf  = (unsigned short*)d_out;
  unsigned short* Kbf  = Qbf + (size_t)(B_ * S_) * E_;

  const int M = B_ * S_;   // 4096
  const int nX8 = (B_ * S_ * E_) / 8;
  const int nW8 = (E_ * E_) / 8;

  convert_all<<<(nX8 + 4 * nW8) / 256, 256, 0, stream>>>(
      X, Wq, Wk, Wv, Wo, Xbf, Wqbf, Wkbf, Wvbf, Wobf);

  gemm128<0><<<(M / 128) * 48, 256, 0, stream>>>(
      Xbf, Wqbf, Wkbf, Wvbf, bq, bk, bv, Qbf, Kbf, Vt, nullptr);

  attnk<<<B_ * H_ * 8, 256, 0, stream>>>(Qbf, Kbf, Vt, Xbf);

  gemm128<1><<<(M / 128) * 16, 256, 0, stream>>>(
      Xbf, Wobf, nullptr, nullptr, bo, nullptr, nullptr,
      nullptr, nullptr, nullptr, out);
}